// Round 13
// baseline (123.545 us; speedup 1.0000x reference)
//
#include <hip/hip_runtime.h>
#include <hip/hip_bf16.h>
#include <cmath>

#define B_   4
#define NT_  2048
#define G_   4096
#define DZ_  128

typedef __attribute__((ext_vector_type(8))) short bf16x8;
typedef __attribute__((ext_vector_type(8))) short s16x8;
typedef __attribute__((ext_vector_type(4))) float f32x4;

__device__ __forceinline__ float softplus_f(float x) {
    return fmaxf(x, 0.0f) + log1pf(expf(-fabsf(x)));
}

// z_grid (B,G,DZ) fp32 -> Zt3 FRAG-MAJOR bf16 tiles (v9 layout, unchanged):
//   Zt3[ ((b*128 + c)*8 + nt)*512 + (q*16 + l15)*8 + j ]
// A B-fragment is a contiguous 1 KB block, lane-contiguous 16 B/lane ->
// global_load_dwordx4 per lane is perfectly coalesced (no LDS needed at all).
__global__ __launch_bounds__(256, 1)
void transpose_z(const float* __restrict__ z, unsigned short* __restrict__ zt)
{
    __shared__ unsigned short tile[64][66];
    const int bx = blockIdx.x;                // 4b * 64gt * 2zt = 512
    const int zti = bx & 1;
    const int gt  = (bx >> 1) & 63;
    const int b   = bx >> 7;
    const int g0 = gt * 64, z0 = zti * 64;
    const int tid = threadIdx.x;
    const int zl = tid & 63, gl = tid >> 6;
    #pragma unroll
    for (int i = 0; i < 16; ++i) {
        const int g = gl + i * 4;
        const float v = z[(size_t)(b * G_ + g0 + g) * DZ_ + z0 + zl];
        unsigned int u = __float_as_uint(v);
        u = u + 0x7FFFu + ((u >> 16) & 1u);   // RNE to bf16
        tile[g][zl] = (unsigned short)(u >> 16);
    }
    __syncthreads();
    const int nt  = tid >> 6;                 // frag (z-block) 0..3 (local)
    const int q   = (tid >> 4) & 3;           // g-octet within chunk
    const int fl  = tid & 15;                 // l15 (z within frag)
    #pragma unroll
    for (int i = 0; i < 2; ++i) {             // chunk-local (c = gt*2 + i)
        s16x8 v;
        #pragma unroll
        for (int j = 0; j < 8; ++j)
            v[j] = (short)tile[i * 32 + q * 8 + j][nt * 16 + fl];
        *(s16x8*)(zt + ((size_t)(b * 128 + gt * 2 + i) * 8 + zti * 4 + nt) * 512
                  + (size_t)(q * 16 + fl) * 8) = v;
    }
}

// v13: NO LDS IN THE MAIN LOOP.  v9's decomposition (512 blocks x 8 waves,
// Tt=16, kh g-split, 4 waves/SIMD) but B-frags stream global->VGPR directly
// (frag-major Zt makes them coalesced 16 B/lane).  bz[8] single-buffered with
// FULL-CHUNK prefetch: loads(ch+1) issue after MFMA(ch) (in-order issue
// resolves the WAR at operand read), so the whole weights(ch+1) phase covers
// L2 latency.  This removes the ~15 us LDS wr+rd pole that v9 paid; remaining
// components: L2 ~15 + VALU ~8 + MFMA ~8.  No barriers, no duplication.
// vs v5b (48 us): that had NO prefetch distance for xv and ran 2 waves/SIMD;
// both diagnosed causes are fixed here.  LDS used only by the reduction.
__global__ __launch_bounds__(512, 4)
void setconv_main(const float* __restrict__ xt,
                  const float* __restrict__ xg,
                  const float* __restrict__ lsp,
                  const unsigned short* __restrict__ Zt,
                  float* __restrict__ out)
{
    __shared__ __align__(16) float red[16384];   // 64 KB, reduction only

    // XCD swizzle: bx = tt2*8 + b*2 + p -> same-b blocks on 2 XCDs
    const int bx = blockIdx.x;
    const int b  = (bx >> 1) & 3;
    const int tt = ((bx >> 3) << 1) | (bx & 1);   // 0..127
    const int tid  = threadIdx.x;
    const int w    = tid >> 6;                // = kh, 0..7
    const int lane = tid & 63;
    const int quad = lane >> 4;
    const int l15  = lane & 15;
    const int t0   = tt * 16;

    float c00, c01, c10, c11;
    {
        const float h = -0.72134752f;         // -0.5*log2(e)
        float ls;
        ls = 1e-5f + softplus_f(lsp[0]); c00 = h / (ls * ls);
        ls = 1e-5f + softplus_f(lsp[1]); c01 = h / (ls * ls);
        ls = 1e-5f + softplus_f(lsp[2]); c10 = h / (ls * ls);
        ls = 1e-5f + softplus_f(lsp[3]); c11 = h / (ls * ls);
    }

    // A-frag row m = l15 -> per-lane t constants
    const float xt0 = xt[(size_t)(b * NT_ + t0 + l15) * 2 + 0];
    const float xt1 = xt[(size_t)(b * NT_ + t0 + l15) * 2 + 1];

    f32x4 acc[2][8];
    #pragma unroll
    for (int k = 0; k < 2; ++k)
        #pragma unroll
        for (int n = 0; n < 8; ++n) acc[k][n] = (f32x4)0.0f;

    // B-frag nt of chunk ch lives at zb + ch*4096 + nt*512 (shorts), 16 B/lane
    const unsigned short* zb = Zt + (size_t)(b * 128 + w * 16) * 4096 + lane * 8;
    const float* xgq = xg + (size_t)(b * G_ + w * 512 + quad * 8) * 2;

    // prologue: xv(0) FIRST (oldest -> weights' wait leaves bz in flight),
    // then bz(0)
    float4 xv0 = *(const float4*)(xgq + 0);
    float4 xv1 = *(const float4*)(xgq + 4);
    float4 xv2 = *(const float4*)(xgq + 8);
    float4 xv3 = *(const float4*)(xgq + 12);
    bf16x8 bz[8];
    #pragma unroll
    for (int nt = 0; nt < 8; ++nt)
        bz[nt] = *(const bf16x8*)(zb + nt * 512);

    #pragma unroll 1
    for (int ch = 0; ch < 16; ++ch) {
        // ---- weights(ch) from xv (loaded >=1 chunk ago; bz stays in flight) ----
        union { bf16x8 v; unsigned int u[4]; } a0, a1;
        #pragma unroll
        for (int jg = 0; jg < 2; ++jg) {
            const float4 xa = jg ? xv2 : xv0;
            const float4 xb = jg ? xv3 : xv1;
            const float px[4] = {xa.x, xa.z, xb.x, xb.z};
            const float py[4] = {xa.y, xa.w, xb.y, xb.w};
            unsigned int w0b[4], w1b[4];
            #pragma unroll
            for (int j = 0; j < 4; ++j) {
                const float d0 = xt0 - px[j];
                const float d1 = xt1 - py[j];
                const float q0 = d0 * d0;
                const float q1 = d1 * d1;
                const float e0 = fmaf(q1, c10, q0 * c00);
                const float e1 = fmaf(q1, c11, q0 * c01);
                w0b[j] = __float_as_uint(__builtin_amdgcn_exp2f(e0));
                w1b[j] = __float_as_uint(__builtin_amdgcn_exp2f(e1));
            }
            a0.u[jg * 2 + 0] = __builtin_amdgcn_perm(w0b[1], w0b[0], 0x07060302u);
            a0.u[jg * 2 + 1] = __builtin_amdgcn_perm(w0b[3], w0b[2], 0x07060302u);
            a1.u[jg * 2 + 0] = __builtin_amdgcn_perm(w1b[1], w1b[0], 0x07060302u);
            a1.u[jg * 2 + 1] = __builtin_amdgcn_perm(w1b[3], w1b[2], 0x07060302u);
        }

        // ---- MFMA(ch): consumes bz (loaded a full weights-phase ago) ----
        __builtin_amdgcn_s_setprio(1);
        #pragma unroll
        for (int nt = 0; nt < 8; ++nt) {
            acc[0][nt] = __builtin_amdgcn_mfma_f32_16x16x32_bf16(a0.v, bz[nt], acc[0][nt], 0, 0, 0);
            acc[1][nt] = __builtin_amdgcn_mfma_f32_16x16x32_bf16(a1.v, bz[nt], acc[1][nt], 0, 0, 0);
        }
        __builtin_amdgcn_s_setprio(0);

        // ---- prefetch chunk ch+1: xv first (older), then bz into the same
        //      regs (WAR resolved at MFMA issue; full next-weights phase of
        //      lead time before consumption) ----
        if (ch < 15) {
            const float* xp = xgq + (ch + 1) * 64;
            xv0 = *(const float4*)(xp + 0);
            xv1 = *(const float4*)(xp + 4);
            xv2 = *(const float4*)(xp + 8);
            xv3 = *(const float4*)(xp + 12);
            const unsigned short* zc = zb + (size_t)(ch + 1) * 4096;
            #pragma unroll
            for (int nt = 0; nt < 8; ++nt)
                bz[nt] = *(const bf16x8*)(zc + nt * 512);
        }
    }

    // ---- 3-round k-reduction over the 8 kh-waves (v9's race-free version) ----
    #define RED_W(slot) { \
        float* bp = &red[(slot) * 4096 + lane * 4]; \
        _Pragma("unroll") \
        for (int k = 0; k < 2; ++k) \
            _Pragma("unroll") \
            for (int n = 0; n < 8; ++n) \
                *(f32x4*)(bp + (k * 8 + n) * 256) = acc[k][n]; }
    #define RED_A(slot) { \
        const float* bp = &red[(slot) * 4096 + lane * 4]; \
        _Pragma("unroll") \
        for (int k = 0; k < 2; ++k) \
            _Pragma("unroll") \
            for (int n = 0; n < 8; ++n) \
                acc[k][n] += *(const f32x4*)(bp + (k * 8 + n) * 256); }

    __syncthreads();
    if (w >= 4) RED_W(w - 4);
    __syncthreads();
    if (w < 4) RED_A(w);
    if (w == 2 || w == 3) RED_W(w);
    __syncthreads();
    if (w < 2) RED_A(w + 2);
    if (w == 1) RED_W(3);
    __syncthreads();
    if (w == 0) {
        RED_A(3);
        const int tr = t0 + quad * 4;
        #pragma unroll
        for (int nt = 0; nt < 8; ++nt) {
            float* ob = out + (size_t)(b * NT_ + tr) * (DZ_ * 2) + (nt * 16 + l15) * 2;
            #pragma unroll
            for (int r = 0; r < 4; ++r)
                *(float2*)(ob + (size_t)r * (DZ_ * 2)) =
                    make_float2(acc[0][nt][r], acc[1][nt][r]);
        }
    }
    #undef RED_W
    #undef RED_A
}

extern "C" void kernel_launch(void* const* d_in, const int* in_sizes, int n_in,
                              void* d_out, int out_size, void* d_ws, size_t ws_size,
                              hipStream_t stream)
{
    const float* x_grid = (const float*)d_in[0];   // (4,64,64,2)
    const float* z_grid = (const float*)d_in[1];   // (4,64,64,128)
    const float* xt     = (const float*)d_in[2];   // (4,2048,2)
    const float* lsp    = (const float*)d_in[3];   // (2,2)
    float* out = (float*)d_out;                    // (4,2048,256) fp32
    unsigned short* Zt = (unsigned short*)d_ws;    // tiled, 4 MB

    hipLaunchKernelGGL(transpose_z, dim3(512), dim3(256), 0, stream, z_grid, Zt);
    hipLaunchKernelGGL(setconv_main, dim3(512), dim3(512), 0, stream,
                       xt, x_grid, lsp, Zt, out);
}